// Round 1
// baseline (297.823 us; speedup 1.0000x reference)
//
#include <hip/hip_runtime.h>

#define NNODE 10000
#define NEDGE 160000
#define DIM   512
#define OUTD  256

using frag8 = __attribute__((ext_vector_type(8))) short;
using f32x4 = __attribute__((ext_vector_type(4))) float;

__device__ __forceinline__ unsigned short f2bf(float f) {
    union { float f; unsigned u; } v; v.f = f;
    unsigned r = (v.u + 0x7fffu + ((v.u >> 16) & 1u)) >> 16;
    return (unsigned short)r;
}
__device__ __forceinline__ float bf2f(unsigned short s) {
    union { unsigned u; float f; } v; v.u = ((unsigned)s) << 16; return v.f;
}

// ---------------- CSR build ----------------
__global__ void k_count(const int* __restrict__ dst, int E, int* __restrict__ deg) {
    int e = blockIdx.x * 256 + threadIdx.x;
    if (e < E) atomicAdd(&deg[dst[e]], 1);
}

__global__ __launch_bounds__(1024) void k_scan(const int* __restrict__ deg,
                                               int* __restrict__ rs,
                                               int* __restrict__ cur, int n) {
    __shared__ int sd[1024];
    const int tid = threadIdx.x;
    int carry = 0;
    for (int base = 0; base < n; base += 1024) {
        int idx = base + tid;
        int v = (idx < n) ? deg[idx] : 0;
        sd[tid] = v;
        __syncthreads();
        for (int off = 1; off < 1024; off <<= 1) {
            int t = (tid >= off) ? sd[tid - off] : 0;
            __syncthreads();
            sd[tid] += t;
            __syncthreads();
        }
        int excl = sd[tid] - v + carry;
        if (idx < n) { rs[idx] = excl; cur[idx] = excl; }
        int total = sd[1023];
        __syncthreads();
        carry += total;
    }
    if (tid == 0) rs[n] = carry;
}

__global__ void k_fill(const int* __restrict__ src, const int* __restrict__ dst,
                       int E, int* __restrict__ cur, int* __restrict__ csr) {
    int e = blockIdx.x * 256 + threadIdx.x;
    if (e < E) {
        int p = atomicAdd(&cur[dst[e]], 1);
        csr[p] = src[e];
    }
}

// ---------------- casts ----------------
__global__ void k_cast4(const float* __restrict__ in, unsigned short* __restrict__ out, int n4) {
    int i = blockIdx.x * 256 + threadIdx.x;
    if (i < n4) {
        float4 f = ((const float4*)in)[i];
        ushort4 o;
        o.x = f2bf(f.x); o.y = f2bf(f.y); o.z = f2bf(f.z); o.w = f2bf(f.w);
        ((ushort4*)out)[i] = o;
    }
}

// Bt[n][k] = (n<H ? wl[k][n] : wr[k][n-H]); K fixed = 512
__global__ void k_cast_w(const float* __restrict__ wl, const float* __restrict__ wr,
                         unsigned short* __restrict__ bt, int H, int total) {
    int i = blockIdx.x * 256 + threadIdx.x;
    if (i < total) {
        int n = i >> 9;        // /512
        int k = i & 511;
        float v = (n < H) ? wl[k * H + n] : wr[k * H + (n - H)];
        bt[i] = f2bf(v);
    }
}

// ---------------- GEMM: C[M x N] = A[M x K](bf16) @ Bt[N x K]^T (bf16), C bf16 ----------------
#define TM 128
#define BK 32
#define LDK 40   // padded row stride in shorts (80B, multiple of 16B, 2-way bank alias = free)

__global__ __launch_bounds__(256) void k_gemm(const unsigned short* __restrict__ A,
                                              const unsigned short* __restrict__ Bt,
                                              unsigned short* __restrict__ C,
                                              int M, int N, int K) {
    __shared__ __align__(16) short As[TM * LDK];
    __shared__ __align__(16) short Bs[TM * LDK];
    const int tid = threadIdx.x;
    const int m0 = blockIdx.x * TM, n0 = blockIdx.y * TM;
    const int wave = tid >> 6, lane = tid & 63;
    const int wm = (wave >> 1) * 64, wn = (wave & 1) * 64;
    const int fr = lane & 15;   // frag row/col in 16
    const int fq = lane >> 4;   // quad
    const int sr = tid >> 2;            // staging row 0..63
    const int sc = (tid & 3) * 8;       // staging col 0,8,16,24

    f32x4 acc[4][4];
#pragma unroll
    for (int i = 0; i < 4; i++)
#pragma unroll
        for (int j = 0; j < 4; j++)
#pragma unroll
            for (int r = 0; r < 4; r++) acc[i][j][r] = 0.f;

    for (int k0 = 0; k0 < K; k0 += BK) {
        __syncthreads();
        {
            int gr0 = m0 + sr, gr1 = m0 + sr + 64;
            frag8 va, vb;
#pragma unroll
            for (int z = 0; z < 8; z++) { va[z] = 0; vb[z] = 0; }
            if (gr0 < M) va = *(const frag8*)(A + (long)gr0 * K + k0 + sc);
            if (gr1 < M) vb = *(const frag8*)(A + (long)gr1 * K + k0 + sc);
            *(frag8*)(As + sr * LDK + sc) = va;
            *(frag8*)(As + (sr + 64) * LDK + sc) = vb;
            frag8 wa = *(const frag8*)(Bt + (long)(n0 + sr) * K + k0 + sc);
            frag8 wb = *(const frag8*)(Bt + (long)(n0 + sr + 64) * K + k0 + sc);
            *(frag8*)(Bs + sr * LDK + sc) = wa;
            *(frag8*)(Bs + (sr + 64) * LDK + sc) = wb;
        }
        __syncthreads();
        frag8 af[4], bf[4];
#pragma unroll
        for (int i = 0; i < 4; i++)
            af[i] = *(const frag8*)(As + (wm + i * 16 + fr) * LDK + fq * 8);
#pragma unroll
        for (int j = 0; j < 4; j++)
            bf[j] = *(const frag8*)(Bs + (wn + j * 16 + fr) * LDK + fq * 8);
#pragma unroll
        for (int i = 0; i < 4; i++)
#pragma unroll
            for (int j = 0; j < 4; j++)
                acc[i][j] = __builtin_amdgcn_mfma_f32_16x16x32_bf16(af[i], bf[j], acc[i][j], 0, 0, 0);
    }

#pragma unroll
    for (int i = 0; i < 4; i++) {
        int row_base = m0 + wm + i * 16 + fq * 4;
#pragma unroll
        for (int j = 0; j < 4; j++) {
            int col = n0 + wn + j * 16 + fr;
#pragma unroll
            for (int r = 0; r < 4; r++) {
                int row = row_base + r;
                if (row < M) C[(long)row * N + col] = f2bf(acc[i][j][r]);
            }
        }
    }
}

// ---------------- aggregation + epilogue ----------------
// TR[M x ncols] bf16: cols [0,hc) = T (to aggregate), cols [hc,2*hc) = R (self part)
// MODE 0: BN+ReLU -> bf16 hout ; MODE 1: plain -> fp32 fout
template <int VEC, int MODE>
__global__ __launch_bounds__(64) void k_agg(const unsigned short* __restrict__ TR, int ncols, int hc,
                                            const int* __restrict__ rs, const int* __restrict__ csr,
                                            const float* __restrict__ bias, const float* __restrict__ gamma,
                                            const float* __restrict__ beta, const float* __restrict__ mean,
                                            const float* __restrict__ var,
                                            unsigned short* __restrict__ hout, float* __restrict__ fout) {
    const int n = blockIdx.x;
    const int c = threadIdx.x * VEC;
    const int s = rs[n], e = rs[n + 1];
    float acc[VEC];
#pragma unroll
    for (int v = 0; v < VEC; v++) acc[v] = 0.f;
    for (int i = s; i < e; i++) {
        const int src = csr[i];
        const unsigned* p = (const unsigned*)(TR + (long)src * ncols + c);
        unsigned u[VEC / 2];
        if constexpr (VEC == 8) {
            uint4 q = *(const uint4*)p; u[0] = q.x; u[1] = q.y; u[2] = q.z; u[3] = q.w;
        } else {
            uint2 q = *(const uint2*)p; u[0] = q.x; u[1] = q.y;
        }
#pragma unroll
        for (int v = 0; v < VEC / 2; v++) {
            acc[2 * v]     += bf2f((unsigned short)(u[v] & 0xffffu));
            acc[2 * v + 1] += bf2f((unsigned short)(u[v] >> 16));
        }
    }
    const int d = e - s;
    const float invd = 1.f / (float)(d > 1 ? d : 1);
    const unsigned* rp = (const unsigned*)(TR + (long)n * ncols + hc + c);
    unsigned ur[VEC / 2];
    if constexpr (VEC == 8) {
        uint4 q = *(const uint4*)rp; ur[0] = q.x; ur[1] = q.y; ur[2] = q.z; ur[3] = q.w;
    } else {
        uint2 q = *(const uint2*)rp; ur[0] = q.x; ur[1] = q.y;
    }
#pragma unroll
    for (int v = 0; v < VEC; v++) {
        float rv = bf2f((unsigned short)((v & 1) ? (ur[v / 2] >> 16) : (ur[v / 2] & 0xffffu)));
        float val = acc[v] * invd + rv + bias[c + v];
        if constexpr (MODE == 0) {
            float y = (val - mean[c + v]) * (gamma[c + v] * rsqrtf(var[c + v] + 1e-5f)) + beta[c + v];
            y = fmaxf(y, 0.f);
            hout[(long)n * hc + c + v] = f2bf(y);
        } else {
            fout[(long)n * hc + c + v] = val;
        }
    }
}

extern "C" void kernel_launch(void* const* d_in, const int* in_sizes, int n_in,
                              void* d_out, int out_size, void* d_ws, size_t ws_size,
                              hipStream_t stream) {
    const float* x    = (const float*)d_in[0];
    const int*   ei   = (const int*)d_in[1];
    const float* w_l1 = (const float*)d_in[2];
    const float* b1   = (const float*)d_in[3];
    const float* w_r1 = (const float*)d_in[4];
    const float* g1   = (const float*)d_in[5];
    const float* be1  = (const float*)d_in[6];
    const float* m1   = (const float*)d_in[7];
    const float* v1   = (const float*)d_in[8];
    const float* w_l2 = (const float*)d_in[9];
    const float* b2   = (const float*)d_in[10];
    const float* w_r2 = (const float*)d_in[11];
    const float* g2   = (const float*)d_in[12];
    const float* be2  = (const float*)d_in[13];
    const float* m2   = (const float*)d_in[14];
    const float* v2   = (const float*)d_in[15];
    const float* w_l3 = (const float*)d_in[16];
    const float* b3   = (const float*)d_in[17];
    const float* w_r3 = (const float*)d_in[18];
    float* out = (float*)d_out;

    const int N = NNODE, E = NEDGE;
    const int* src = ei;
    const int* dst = ei + E;

    char* w = (char*)d_ws;
    auto alloc = [&](size_t bytes) { void* p = (void*)w; w += (bytes + 255) & ~(size_t)255; return p; };
    int* deg = (int*)alloc((size_t)N * 4);
    int* rs  = (int*)alloc((size_t)(N + 1) * 4);
    int* cur = (int*)alloc((size_t)N * 4);
    int* csr = (int*)alloc((size_t)E * 4);
    unsigned short* xb  = (unsigned short*)alloc((size_t)N * DIM * 2);
    unsigned short* w1t = (unsigned short*)alloc((size_t)1024 * DIM * 2);
    unsigned short* w2t = (unsigned short*)alloc((size_t)1024 * DIM * 2);
    unsigned short* w3t = (unsigned short*)alloc((size_t)512 * DIM * 2);
    unsigned short* tr  = (unsigned short*)alloc((size_t)N * 1024 * 2);
    unsigned short* h   = (unsigned short*)alloc((size_t)N * DIM * 2);

    hipMemsetAsync(deg, 0, (size_t)N * 4, stream);
    k_count<<<(E + 255) / 256, 256, 0, stream>>>(dst, E, deg);
    k_scan<<<1, 1024, 0, stream>>>(deg, rs, cur, N);
    k_fill<<<(E + 255) / 256, 256, 0, stream>>>(src, dst, E, cur, csr);

    k_cast4<<<(N * DIM / 4 + 255) / 256, 256, 0, stream>>>(x, xb, N * DIM / 4);
    k_cast_w<<<(2 * 512 * 512 + 255) / 256, 256, 0, stream>>>(w_l1, w_r1, w1t, 512, 2 * 512 * 512);
    k_cast_w<<<(2 * 512 * 512 + 255) / 256, 256, 0, stream>>>(w_l2, w_r2, w2t, 512, 2 * 512 * 512);
    k_cast_w<<<(2 * 256 * 512 + 255) / 256, 256, 0, stream>>>(w_l3, w_r3, w3t, 256, 2 * 256 * 512);

    dim3 gg((N + TM - 1) / TM, 1024 / TM);   // (79, 8)
    dim3 g3((N + TM - 1) / TM, 512 / TM);    // (79, 4)

    // Layer 1
    k_gemm<<<gg, 256, 0, stream>>>(xb, w1t, tr, N, 1024, 512);
    k_agg<8, 0><<<N, 64, 0, stream>>>(tr, 1024, 512, rs, csr, b1, g1, be1, m1, v1, h, nullptr);
    // Layer 2
    k_gemm<<<gg, 256, 0, stream>>>(h, w2t, tr, N, 1024, 512);
    k_agg<8, 0><<<N, 64, 0, stream>>>(tr, 1024, 512, rs, csr, b2, g2, be2, m2, v2, h, nullptr);
    // Layer 3
    k_gemm<<<g3, 256, 0, stream>>>(h, w3t, tr, N, 512, 512);
    k_agg<4, 1><<<N, 64, 0, stream>>>(tr, 512, 256, rs, csr, b3, nullptr, nullptr, nullptr, nullptr, nullptr, out);
}

// Round 2
// 278.965 us; speedup vs baseline: 1.0676x; 1.0676x over previous
//
#include <hip/hip_runtime.h>

#define NNODE 10000
#define NEDGE 160000
#define DIM   512
#define OUTD  256

using frag8 = __attribute__((ext_vector_type(8))) short;
using f32x4 = __attribute__((ext_vector_type(4))) float;

__device__ __forceinline__ unsigned short f2bf(float f) {
    union { float f; unsigned u; } v; v.f = f;
    unsigned r = (v.u + 0x7fffu + ((v.u >> 16) & 1u)) >> 16;
    return (unsigned short)r;
}
__device__ __forceinline__ float bf2f(unsigned short s) {
    union { unsigned u; float f; } v; v.u = ((unsigned)s) << 16; return v.f;
}

// ---------------- CSR build ----------------
__global__ void k_count(const int* __restrict__ dst, int E, int* __restrict__ deg) {
    int e = blockIdx.x * 256 + threadIdx.x;
    if (e < E) atomicAdd(&deg[dst[e]], 1);
}

// single block, 1024 threads, each owns 10 contiguous elements; 2 barriers total
__global__ __launch_bounds__(1024) void k_scan(const int* __restrict__ deg,
                                               int* __restrict__ rs,
                                               int* __restrict__ cur, int n, int total) {
    const int tid = threadIdx.x;
    const int CH = 10;                       // 1024*10 = 10240 >= n
    const int base = tid * CH;
    int vals[CH];
    int tsum = 0;
#pragma unroll
    for (int j = 0; j < CH; j++) {
        int v = (base + j < n) ? deg[base + j] : 0;
        vals[j] = v; tsum += v;
    }
    const int lane = tid & 63, wid = tid >> 6;
    int x = tsum;
#pragma unroll
    for (int d = 1; d < 64; d <<= 1) {
        int y = __shfl_up(x, d, 64);
        if (lane >= d) x += y;
    }
    __shared__ int wt[16];
    if (lane == 63) wt[wid] = x;
    __syncthreads();
    if (tid == 0) {
        int c = 0;
#pragma unroll
        for (int k = 0; k < 16; k++) { int t = wt[k]; wt[k] = c; c += t; }
    }
    __syncthreads();
    int run = wt[wid] + x - tsum;            // exclusive prefix for this thread's chunk
#pragma unroll
    for (int j = 0; j < CH; j++) {
        if (base + j < n) { rs[base + j] = run; cur[base + j] = run; }
        run += vals[j];
    }
    if (tid == 0) rs[n] = total;
}

__global__ void k_fill(const int* __restrict__ src, const int* __restrict__ dst,
                       int E, int* __restrict__ cur, int* __restrict__ csr) {
    int e = blockIdx.x * 256 + threadIdx.x;
    if (e < E) {
        int p = atomicAdd(&cur[dst[e]], 1);
        csr[p] = src[e];
    }
}

// ---------------- casts ----------------
__global__ void k_cast4(const float* __restrict__ in, unsigned short* __restrict__ out, int n4) {
    int i = blockIdx.x * 256 + threadIdx.x;
    if (i < n4) {
        float4 f = ((const float4*)in)[i];
        ushort4 o;
        o.x = f2bf(f.x); o.y = f2bf(f.y); o.z = f2bf(f.z); o.w = f2bf(f.w);
        ((ushort4*)out)[i] = o;
    }
}

// all three fused-weight transposes in one launch. bt[n][k] = (n<H ? wl[k][n] : wr[k][n-H])
__global__ void k_cast_w_all(const float* __restrict__ wl1, const float* __restrict__ wr1,
                             const float* __restrict__ wl2, const float* __restrict__ wr2,
                             const float* __restrict__ wl3, const float* __restrict__ wr3,
                             unsigned short* __restrict__ bt1, unsigned short* __restrict__ bt2,
                             unsigned short* __restrict__ bt3) {
    int i = blockIdx.x * 256 + threadIdx.x;
    const int S = 1024 * 512;
    const float *wl, *wr; unsigned short* bt; int H; int j;
    if (i < S)           { wl = wl1; wr = wr1; bt = bt1; H = 512; j = i; }
    else if (i < 2 * S)  { wl = wl2; wr = wr2; bt = bt2; H = 512; j = i - S; }
    else                 { wl = wl3; wr = wr3; bt = bt3; H = 256; j = i - 2 * S;
                           if (j >= 512 * 512) return; }
    int n = j >> 9, k = j & 511;
    float v = (n < H) ? wl[k * H + n] : wr[k * H + (n - H)];
    bt[j] = f2bf(v);
}

// ---------------- GEMM: C[M x N] = A[M x K](bf16) @ Bt[N x K]^T (bf16), C bf16 ----------------
// 128x128 tile, BK=64, global_load_lds(16B) staging with XOR-swizzled source columns.
#define TM 128
#define BKK 64

__global__ __launch_bounds__(256) void k_gemm(const unsigned short* __restrict__ A,
                                              const unsigned short* __restrict__ Bt,
                                              unsigned short* __restrict__ C,
                                              int M, int N, int K) {
    __shared__ __align__(16) short As[TM * BKK];
    __shared__ __align__(16) short Bs[TM * BKK];
    const int tid = threadIdx.x;
    const int m0 = blockIdx.x * TM, n0 = blockIdx.y * TM;
    const int w = tid >> 6, lane = tid & 63;
    const int wm = (w >> 1) * 64, wn = (w & 1) * 64;
    const int fr = lane & 15;       // m/n within 16
    const int fq = lane >> 4;       // k quad
    const int sw = fr & 7;          // row swizzle key (R & 7 == fr & 7 for all frag rows)

    // staging: chunk c covers rows c*32 + w*8 + (lane>>3); lane stores 16B to slot lane&7,
    // which must hold global col-block (slot ^ (row&7)) -> swizzle applied to SOURCE column.
    const int srow = w * 8 + (lane >> 3);                 // 0..31 (+ c*32)
    const int scol = (((lane & 7) ^ (lane >> 3)) * 8);    // shorts
    const short* pa = (const short*)A + (long)(m0 + srow) * K + scol;
    const short* pb = (const short*)Bt + (long)(n0 + srow) * K + scol;
    short* asDst = As + w * 8 * BKK;
    short* bsDst = Bs + w * 8 * BKK;

    f32x4 acc[4][4];
#pragma unroll
    for (int i = 0; i < 4; i++)
#pragma unroll
        for (int j = 0; j < 4; j++)
#pragma unroll
            for (int r = 0; r < 4; r++) acc[i][j][r] = 0.f;

    for (int k0 = 0; k0 < K; k0 += BKK) {
        __syncthreads();
#pragma unroll
        for (int c = 0; c < 4; c++) {
            __builtin_amdgcn_global_load_lds(
                (const __attribute__((address_space(1))) void*)(pa + (long)c * 32 * K + k0),
                (__attribute__((address_space(3))) void*)(asDst + c * 32 * BKK), 16, 0, 0);
            __builtin_amdgcn_global_load_lds(
                (const __attribute__((address_space(1))) void*)(pb + (long)c * 32 * K + k0),
                (__attribute__((address_space(3))) void*)(bsDst + c * 32 * BKK), 16, 0, 0);
        }
        __syncthreads();
#pragma unroll
        for (int ks = 0; ks < 2; ks++) {
            frag8 af[4], bf[4];
#pragma unroll
            for (int i = 0; i < 4; i++) {
                int R = wm + i * 16 + fr;
                af[i] = *(const frag8*)(As + R * BKK + (((ks * 4 + fq) ^ sw) * 8));
            }
#pragma unroll
            for (int j = 0; j < 4; j++) {
                int R = wn + j * 16 + fr;
                bf[j] = *(const frag8*)(Bs + R * BKK + (((ks * 4 + fq) ^ sw) * 8));
            }
#pragma unroll
            for (int i = 0; i < 4; i++)
#pragma unroll
                for (int j = 0; j < 4; j++)
                    acc[i][j] = __builtin_amdgcn_mfma_f32_16x16x32_bf16(af[i], bf[j], acc[i][j], 0, 0, 0);
        }
    }

#pragma unroll
    for (int i = 0; i < 4; i++) {
        int row_base = m0 + wm + i * 16 + fq * 4;
#pragma unroll
        for (int j = 0; j < 4; j++) {
            int col = n0 + wn + j * 16 + fr;
#pragma unroll
            for (int r = 0; r < 4; r++) {
                int row = row_base + r;
                if (row < M) C[(long)row * N + col] = f2bf(acc[i][j][r]);
            }
        }
    }
}

// ---------------- aggregation + epilogue ----------------
// TR[M x ncols] bf16: cols [0,hc) = T (aggregate over sources), cols [hc,2*hc) = R (self)
// MODE 0: BN+ReLU -> bf16 hout ; MODE 1: plain -> fp32 fout
template <int VEC, int MODE>
__global__ __launch_bounds__(64) void k_agg(const unsigned short* __restrict__ TR, int ncols, int hc,
                                            const int* __restrict__ rs, const int* __restrict__ csr,
                                            const float* __restrict__ bias, const float* __restrict__ gamma,
                                            const float* __restrict__ beta, const float* __restrict__ mean,
                                            const float* __restrict__ var,
                                            unsigned short* __restrict__ hout, float* __restrict__ fout) {
    const int n = blockIdx.x;
    const int lane = threadIdx.x;
    const int c = lane * VEC;
    const int s = rs[n], e = rs[n + 1];
    const int cnt = e - s;
    float acc[VEC];
#pragma unroll
    for (int v = 0; v < VEC; v++) acc[v] = 0.f;

    int myidx = (s + lane < e) ? csr[s + lane] : 0;   // coalesced batch of indices
#pragma unroll 2
    for (int i = 0; i < cnt; i++) {
        const int ii = i & 63;
        if (i && ii == 0) myidx = (s + i + lane < e) ? csr[s + i + lane] : 0;
        const int src = __shfl(myidx, ii, 64);
        const unsigned* p = (const unsigned*)(TR + (long)src * ncols + c);
        unsigned u[VEC / 2];
        if constexpr (VEC == 8) {
            uint4 q = *(const uint4*)p; u[0] = q.x; u[1] = q.y; u[2] = q.z; u[3] = q.w;
        } else {
            uint2 q = *(const uint2*)p; u[0] = q.x; u[1] = q.y;
        }
#pragma unroll
        for (int v = 0; v < VEC / 2; v++) {
            acc[2 * v]     += bf2f((unsigned short)(u[v] & 0xffffu));
            acc[2 * v + 1] += bf2f((unsigned short)(u[v] >> 16));
        }
    }
    const float invd = 1.f / (float)(cnt > 1 ? cnt : 1);
    const unsigned* rp = (const unsigned*)(TR + (long)n * ncols + hc + c);
    unsigned ur[VEC / 2];
    if constexpr (VEC == 8) {
        uint4 q = *(const uint4*)rp; ur[0] = q.x; ur[1] = q.y; ur[2] = q.z; ur[3] = q.w;
    } else {
        uint2 q = *(const uint2*)rp; ur[0] = q.x; ur[1] = q.y;
    }
#pragma unroll
    for (int v = 0; v < VEC; v++) {
        float rv = bf2f((unsigned short)((v & 1) ? (ur[v / 2] >> 16) : (ur[v / 2] & 0xffffu)));
        float val = acc[v] * invd + rv + bias[c + v];
        if constexpr (MODE == 0) {
            float y = (val - mean[c + v]) * (gamma[c + v] * rsqrtf(var[c + v] + 1e-5f)) + beta[c + v];
            y = fmaxf(y, 0.f);
            hout[(long)n * hc + c + v] = f2bf(y);
        } else {
            fout[(long)n * hc + c + v] = val;
        }
    }
}

extern "C" void kernel_launch(void* const* d_in, const int* in_sizes, int n_in,
                              void* d_out, int out_size, void* d_ws, size_t ws_size,
                              hipStream_t stream) {
    const float* x    = (const float*)d_in[0];
    const int*   ei   = (const int*)d_in[1];
    const float* w_l1 = (const float*)d_in[2];
    const float* b1   = (const float*)d_in[3];
    const float* w_r1 = (const float*)d_in[4];
    const float* g1   = (const float*)d_in[5];
    const float* be1  = (const float*)d_in[6];
    const float* m1   = (const float*)d_in[7];
    const float* v1   = (const float*)d_in[8];
    const float* w_l2 = (const float*)d_in[9];
    const float* b2   = (const float*)d_in[10];
    const float* w_r2 = (const float*)d_in[11];
    const float* g2   = (const float*)d_in[12];
    const float* be2  = (const float*)d_in[13];
    const float* m2   = (const float*)d_in[14];
    const float* v2   = (const float*)d_in[15];
    const float* w_l3 = (const float*)d_in[16];
    const float* b3   = (const float*)d_in[17];
    const float* w_r3 = (const float*)d_in[18];
    float* out = (float*)d_out;

    const int N = NNODE, E = NEDGE;
    const int* src = ei;
    const int* dst = ei + E;

    char* w = (char*)d_ws;
    auto alloc = [&](size_t bytes) { void* p = (void*)w; w += (bytes + 255) & ~(size_t)255; return p; };
    int* deg = (int*)alloc((size_t)N * 4);
    int* rs  = (int*)alloc((size_t)(N + 1) * 4);
    int* cur = (int*)alloc((size_t)N * 4);
    int* csr = (int*)alloc((size_t)E * 4);
    unsigned short* xb  = (unsigned short*)alloc((size_t)N * DIM * 2);
    unsigned short* w1t = (unsigned short*)alloc((size_t)1024 * DIM * 2);
    unsigned short* w2t = (unsigned short*)alloc((size_t)1024 * DIM * 2);
    unsigned short* w3t = (unsigned short*)alloc((size_t)512 * DIM * 2);
    unsigned short* tr  = (unsigned short*)alloc((size_t)N * 1024 * 2);
    unsigned short* h   = (unsigned short*)alloc((size_t)N * DIM * 2);
    (void)alloc(256 * 1024);  // tail slack: last M-tile GEMM DMA over-reads ~114KB past A

    hipMemsetAsync(deg, 0, (size_t)N * 4, stream);
    k_count<<<(E + 255) / 256, 256, 0, stream>>>(dst, E, deg);
    k_scan<<<1, 1024, 0, stream>>>(deg, rs, cur, N, E);
    k_fill<<<(E + 255) / 256, 256, 0, stream>>>(src, dst, E, cur, csr);

    k_cast4<<<(N * DIM / 4 + 255) / 256, 256, 0, stream>>>(x, xb, N * DIM / 4);
    {
        int total = 2 * 1024 * 512 + 512 * 512;
        k_cast_w_all<<<(total + 255) / 256, 256, 0, stream>>>(w_l1, w_r1, w_l2, w_r2, w_l3, w_r3,
                                                              w1t, w2t, w3t);
    }

    dim3 gg((N + TM - 1) / TM, 1024 / TM);   // (79, 8)
    dim3 g3((N + TM - 1) / TM, 512 / TM);    // (79, 4)

    // Layer 1
    k_gemm<<<gg, 256, 0, stream>>>(xb, w1t, tr, N, 1024, 512);
    k_agg<8, 0><<<N, 64, 0, stream>>>(tr, 1024, 512, rs, csr, b1, g1, be1, m1, v1, h, nullptr);
    // Layer 2
    k_gemm<<<gg, 256, 0, stream>>>(h, w2t, tr, N, 1024, 512);
    k_agg<8, 0><<<N, 64, 0, stream>>>(tr, 1024, 512, rs, csr, b2, g2, be2, m2, v2, h, nullptr);
    // Layer 3 (output fp32)
    k_gemm<<<g3, 256, 0, stream>>>(h, w3t, tr, N, 512, 512);
    k_agg<4, 1><<<N, 64, 0, stream>>>(tr, 512, 256, rs, csr, b3, nullptr, nullptr, nullptr, nullptr, nullptr, out);
}

// Round 3
// 275.859 us; speedup vs baseline: 1.0796x; 1.0113x over previous
//
#include <hip/hip_runtime.h>

#define NNODE 10000
#define NEDGE 160000

using frag8 = __attribute__((ext_vector_type(8))) short;
using f32x4 = __attribute__((ext_vector_type(4))) float;

__device__ __forceinline__ unsigned short f2bf(float f) {
    union { float f; unsigned u; } v; v.f = f;
    unsigned r = (v.u + 0x7fffu + ((v.u >> 16) & 1u)) >> 16;
    return (unsigned short)r;
}
__device__ __forceinline__ float bf2f(unsigned short s) {
    union { unsigned u; float f; } v; v.u = ((unsigned)s) << 16; return v.f;
}

// ---------------- CSR build ----------------
__global__ void k_count(const int* __restrict__ dst, int E, int* __restrict__ deg) {
    int e = blockIdx.x * 256 + threadIdx.x;
    if (e < E) atomicAdd(&deg[dst[e]], 1);
}

__global__ __launch_bounds__(1024) void k_scan(const int* __restrict__ deg,
                                               int* __restrict__ rs,
                                               int* __restrict__ cur, int n, int total) {
    const int tid = threadIdx.x;
    const int CH = 10;
    const int base = tid * CH;
    int vals[CH];
    int tsum = 0;
#pragma unroll
    for (int j = 0; j < CH; j++) {
        int v = (base + j < n) ? deg[base + j] : 0;
        vals[j] = v; tsum += v;
    }
    const int lane = tid & 63, wid = tid >> 6;
    int x = tsum;
#pragma unroll
    for (int d = 1; d < 64; d <<= 1) {
        int y = __shfl_up(x, d, 64);
        if (lane >= d) x += y;
    }
    __shared__ int wt[16];
    if (lane == 63) wt[wid] = x;
    __syncthreads();
    if (tid == 0) {
        int c = 0;
#pragma unroll
        for (int k = 0; k < 16; k++) { int t = wt[k]; wt[k] = c; c += t; }
    }
    __syncthreads();
    int run = wt[wid] + x - tsum;
#pragma unroll
    for (int j = 0; j < CH; j++) {
        if (base + j < n) { rs[base + j] = run; cur[base + j] = run; }
        run += vals[j];
    }
    if (tid == 0) rs[n] = total;
}

__global__ void k_fill(const int* __restrict__ src, const int* __restrict__ dst,
                       int E, int* __restrict__ cur, int* __restrict__ csr) {
    int e = blockIdx.x * 256 + threadIdx.x;
    if (e < E) {
        int p = atomicAdd(&cur[dst[e]], 1);
        csr[p] = src[e];
    }
}

// ---------------- fused prep: x-cast + 6 weight transposes + scale/shift ----------------
// blocks [0,5000): cast x (fp32->bf16), [5000,6280): LDS-tiled transposes, 6280: scale/shift
__global__ __launch_bounds__(256) void k_prep(
    const float* __restrict__ x, unsigned short* __restrict__ xb,
    const float* __restrict__ wl1, const float* __restrict__ wr1,
    const float* __restrict__ wl2, const float* __restrict__ wr2,
    const float* __restrict__ wl3, const float* __restrict__ wr3,
    unsigned short* __restrict__ bt1, unsigned short* __restrict__ bt2,
    unsigned short* __restrict__ bt3,
    const float* __restrict__ b1, const float* __restrict__ g1, const float* __restrict__ be1,
    const float* __restrict__ m1, const float* __restrict__ v1,
    const float* __restrict__ b2, const float* __restrict__ g2, const float* __restrict__ be2,
    const float* __restrict__ m2, const float* __restrict__ v2,
    const float* __restrict__ b3,
    float* __restrict__ sc1, float* __restrict__ sh1,
    float* __restrict__ sc2, float* __restrict__ sh2,
    float* __restrict__ sc3, float* __restrict__ sh3) {
    const int b = blockIdx.x, tid = threadIdx.x;
    if (b < 5000) {                       // x cast: 5000*256*4 = 5.12M elems = N*512
        int i = b * 256 + tid;            // float4 index
        float4 f = ((const float4*)x)[i];
        ushort4 o;
        o.x = f2bf(f.x); o.y = f2bf(f.y); o.z = f2bf(f.z); o.w = f2bf(f.w);
        ((ushort4*)xb)[i] = o;
        return;
    }
    if (b == 6280) {                      // scale/shift
        // layer1/2: 512 each; layer3: 256
        for (int t = tid; t < 512; t += 256) {
            float s1 = g1[t] * rsqrtf(v1[t] + 1e-5f);
            sc1[t] = s1; sh1[t] = (b1[t] - m1[t]) * s1 + be1[t];
            float s2 = g2[t] * rsqrtf(v2[t] + 1e-5f);
            sc2[t] = s2; sh2[t] = (b2[t] - m2[t]) * s2 + be2[t];
        }
        if (tid < 256) { sc3[tid] = 1.0f; sh3[tid] = b3[tid]; }
        return;
    }
    // transposes: dst[n*1024 + koff + k] = src[k*C + n]
    __shared__ float t[32][33];
    int tj = b - 5000;
    const float* srcp; unsigned short* dstp; int C, koff, ntilesN;
    if (tj < 1024) {
        int job = tj >> 8; int tile = tj & 255; C = 512; ntilesN = 16;
        srcp = (job == 0) ? wl1 : (job == 1) ? wr1 : (job == 2) ? wl2 : wr2;
        dstp = (job < 2) ? bt1 : bt2; koff = (job & 1) * 512;
        tj = tile;
    } else {
        int jj = tj - 1024; int job = jj >> 7; int tile = jj & 127; C = 256; ntilesN = 8;
        srcp = (job == 0) ? wl3 : wr3; dstp = bt3; koff = job * 512;
        tj = tile;
    }
    int k0 = (tj / ntilesN) * 32, c0 = (tj % ntilesN) * 32;
    int tx = tid & 31, ty = tid >> 5;
#pragma unroll
    for (int q = 0; q < 4; q++)
        t[ty + 8 * q][tx] = srcp[(long)(k0 + ty + 8 * q) * C + c0 + tx];
    __syncthreads();
#pragma unroll
    for (int q = 0; q < 4; q++)
        dstp[(long)(c0 + ty + 8 * q) * 1024 + koff + k0 + tx] = f2bf(t[tx][ty + 8 * q]);
}

// ---------------- aggregation: 4 column passes, L2-resident ----------------
// S: [N x 512] bf16 source features; out[n*512+c] = mean over neighbors
__global__ __launch_bounds__(64) void k_agg(const unsigned short* __restrict__ S,
                                            const int* __restrict__ rs, const int* __restrict__ csr,
                                            unsigned short* __restrict__ outb) {
    const int n = blockIdx.x;
    const int c = blockIdx.y * 128 + threadIdx.x * 2;   // pass = blockIdx.y (dispatch-ordered)
    const int s = rs[n], e = rs[n + 1];
    float a0 = 0.f, a1 = 0.f;
    int i = s;
    for (; i + 4 <= e; i += 4) {
        int r0 = csr[i], r1 = csr[i + 1], r2 = csr[i + 2], r3 = csr[i + 3];
        unsigned u0 = *(const unsigned*)(S + (long)r0 * 512 + c);
        unsigned u1 = *(const unsigned*)(S + (long)r1 * 512 + c);
        unsigned u2 = *(const unsigned*)(S + (long)r2 * 512 + c);
        unsigned u3 = *(const unsigned*)(S + (long)r3 * 512 + c);
        a0 += bf2f((unsigned short)(u0 & 0xffffu)); a1 += bf2f((unsigned short)(u0 >> 16));
        a0 += bf2f((unsigned short)(u1 & 0xffffu)); a1 += bf2f((unsigned short)(u1 >> 16));
        a0 += bf2f((unsigned short)(u2 & 0xffffu)); a1 += bf2f((unsigned short)(u2 >> 16));
        a0 += bf2f((unsigned short)(u3 & 0xffffu)); a1 += bf2f((unsigned short)(u3 >> 16));
    }
    for (; i < e; i++) {
        unsigned u = *(const unsigned*)(S + (long)csr[i] * 512 + c);
        a0 += bf2f((unsigned short)(u & 0xffffu)); a1 += bf2f((unsigned short)(u >> 16));
    }
    const int cnt = e - s;
    const float inv = 1.f / (float)(cnt > 1 ? cnt : 1);
    unsigned o = (unsigned)f2bf(a0 * inv) | ((unsigned)f2bf(a1 * inv) << 16);
    *(unsigned*)(outb + (long)n * 512 + c) = o;
}

// ---------------- GEMM: C[M x NOUT] = [Agg|Self][M x 1024] @ Bt[NOUT x 1024]^T ----------------
// 128x64 tile, BK=64, global_load_lds(16B) with XOR-swizzled source columns.
// MODE 0: y = relu(dot*sc+sh) -> bf16 (stride 512). MODE 1: y = dot*sc+sh -> fp32 (stride 256).
template <int MODE, int NOUT>
__global__ __launch_bounds__(256) void k_gemm(const unsigned short* __restrict__ Agg,
                                              const unsigned short* __restrict__ Self,
                                              const unsigned short* __restrict__ Bt,
                                              const float* __restrict__ sc, const float* __restrict__ sh,
                                              unsigned short* __restrict__ hout, float* __restrict__ fout,
                                              int M) {
    __shared__ __align__(16) short As[128 * 64];
    __shared__ __align__(16) short Bs[64 * 64];
    const int tid = threadIdx.x;
    const int m0 = blockIdx.x * 128, n0 = blockIdx.y * 64;
    const int w = tid >> 6, lane = tid & 63;
    const int wm = (w >> 1) * 64, wn = (w & 1) * 32;
    const int fr = lane & 15;
    const int fq = lane >> 4;
    const int sw = fr & 7;

    const int srow = w * 8 + (lane >> 3);
    const int scol = (((lane & 7) ^ (lane >> 3)) * 8);
    short* asDst = As + w * 8 * 64;
    short* bsDst = Bs + w * 8 * 64;

    f32x4 acc[4][2];
#pragma unroll
    for (int i = 0; i < 4; i++)
#pragma unroll
        for (int j = 0; j < 2; j++)
#pragma unroll
            for (int r = 0; r < 4; r++) acc[i][j][r] = 0.f;

    for (int k0 = 0; k0 < 1024; k0 += 64) {
        const short* abase = (const short*)((k0 < 512) ? Agg : Self);
        const int kk = k0 & 511;
        __syncthreads();
#pragma unroll
        for (int cch = 0; cch < 4; cch++)
            __builtin_amdgcn_global_load_lds(
                (const __attribute__((address_space(1))) void*)(abase + (long)(m0 + cch * 32 + srow) * 512 + kk + scol),
                (__attribute__((address_space(3))) void*)(asDst + cch * 32 * 64), 16, 0, 0);
#pragma unroll
        for (int cch = 0; cch < 2; cch++)
            __builtin_amdgcn_global_load_lds(
                (const __attribute__((address_space(1))) void*)((const short*)Bt + (long)(n0 + cch * 32 + srow) * 1024 + k0 + scol),
                (__attribute__((address_space(3))) void*)(bsDst + cch * 32 * 64), 16, 0, 0);
        __syncthreads();
#pragma unroll
        for (int ks = 0; ks < 2; ks++) {
            frag8 af[4], bf[2];
#pragma unroll
            for (int i = 0; i < 4; i++)
                af[i] = *(const frag8*)(As + (wm + i * 16 + fr) * 64 + (((ks * 4 + fq) ^ sw) * 8));
#pragma unroll
            for (int j = 0; j < 2; j++)
                bf[j] = *(const frag8*)(Bs + (wn + j * 16 + fr) * 64 + (((ks * 4 + fq) ^ sw) * 8));
#pragma unroll
            for (int i = 0; i < 4; i++)
#pragma unroll
                for (int j = 0; j < 2; j++)
                    acc[i][j] = __builtin_amdgcn_mfma_f32_16x16x32_bf16(af[i], bf[j], acc[i][j], 0, 0, 0);
        }
    }

    float scj[2], shj[2];
#pragma unroll
    for (int j = 0; j < 2; j++) {
        int col = n0 + wn + j * 16 + fr;
        scj[j] = sc[col]; shj[j] = sh[col];
    }
#pragma unroll
    for (int i = 0; i < 4; i++) {
        int rowb = m0 + wm + i * 16 + fq * 4;
#pragma unroll
        for (int j = 0; j < 2; j++) {
            int col = n0 + wn + j * 16 + fr;
#pragma unroll
            for (int r = 0; r < 4; r++) {
                int row = rowb + r;
                if (row < M) {
                    float y = acc[i][j][r] * scj[j] + shj[j];
                    if constexpr (MODE == 0) {
                        y = fmaxf(y, 0.f);
                        hout[(long)row * 512 + col] = f2bf(y);
                    } else {
                        fout[(long)row * NOUT + col] = y;
                    }
                }
            }
        }
    }
}

extern "C" void kernel_launch(void* const* d_in, const int* in_sizes, int n_in,
                              void* d_out, int out_size, void* d_ws, size_t ws_size,
                              hipStream_t stream) {
    const float* x    = (const float*)d_in[0];
    const int*   ei   = (const int*)d_in[1];
    const float* w_l1 = (const float*)d_in[2];
    const float* b1   = (const float*)d_in[3];
    const float* w_r1 = (const float*)d_in[4];
    const float* g1   = (const float*)d_in[5];
    const float* be1  = (const float*)d_in[6];
    const float* m1   = (const float*)d_in[7];
    const float* v1   = (const float*)d_in[8];
    const float* w_l2 = (const float*)d_in[9];
    const float* b2   = (const float*)d_in[10];
    const float* w_r2 = (const float*)d_in[11];
    const float* g2   = (const float*)d_in[12];
    const float* be2  = (const float*)d_in[13];
    const float* m2   = (const float*)d_in[14];
    const float* v2   = (const float*)d_in[15];
    const float* w_l3 = (const float*)d_in[16];
    const float* b3   = (const float*)d_in[17];
    const float* w_r3 = (const float*)d_in[18];
    float* out = (float*)d_out;

    const int N = NNODE, E = NEDGE;
    const int* srcI = ei;
    const int* dstI = ei + E;

    char* w = (char*)d_ws;
    auto alloc = [&](size_t bytes) { void* p = (void*)w; w += (bytes + 255) & ~(size_t)255; return p; };
    int* deg = (int*)alloc((size_t)N * 4);
    int* rs  = (int*)alloc((size_t)(N + 1) * 4);
    int* cur = (int*)alloc((size_t)N * 4);
    int* csr = (int*)alloc((size_t)E * 4);
    unsigned short* xb   = (unsigned short*)alloc((size_t)N * 512 * 2);
    unsigned short* bt1  = (unsigned short*)alloc((size_t)512 * 1024 * 2);
    unsigned short* bt2  = (unsigned short*)alloc((size_t)512 * 1024 * 2);
    unsigned short* bt3  = (unsigned short*)alloc((size_t)256 * 1024 * 2);
    float* sc1 = (float*)alloc(512 * 4); float* sh1 = (float*)alloc(512 * 4);
    float* sc2 = (float*)alloc(512 * 4); float* sh2 = (float*)alloc(512 * 4);
    float* sc3 = (float*)alloc(256 * 4); float* sh3 = (float*)alloc(256 * 4);
    unsigned short* agg_a = (unsigned short*)alloc((size_t)N * 512 * 2);
    unsigned short* h1    = (unsigned short*)alloc((size_t)N * 512 * 2);
    unsigned short* h2    = (unsigned short*)alloc((size_t)N * 512 * 2);
    (void)alloc(256 * 1024);  // DMA over-read slack for last M-tile

    hipMemsetAsync(deg, 0, (size_t)N * 4, stream);
    k_count<<<(E + 255) / 256, 256, 0, stream>>>(dstI, E, deg);
    k_scan<<<1, 1024, 0, stream>>>(deg, rs, cur, N, E);
    k_fill<<<(E + 255) / 256, 256, 0, stream>>>(srcI, dstI, E, cur, csr);
    k_prep<<<6281, 256, 0, stream>>>(x, xb, w_l1, w_r1, w_l2, w_r2, w_l3, w_r3,
                                     bt1, bt2, bt3,
                                     b1, g1, be1, m1, v1, b2, g2, be2, m2, v2, b3,
                                     sc1, sh1, sc2, sh2, sc3, sh3);

    dim3 g12((N + 127) / 128, 8);   // (79, 8) -> NOUT=512
    dim3 g3((N + 127) / 128, 4);    // (79, 4) -> NOUT=256
    dim3 ga(N, 4);

    // Layer 1
    k_agg<<<ga, 64, 0, stream>>>(xb, rs, csr, agg_a);
    k_gemm<0, 512><<<g12, 256, 0, stream>>>(agg_a, xb, bt1, sc1, sh1, h1, nullptr, N);
    // Layer 2
    k_agg<<<ga, 64, 0, stream>>>(h1, rs, csr, agg_a);
    k_gemm<0, 512><<<g12, 256, 0, stream>>>(agg_a, h1, bt2, sc2, sh2, h2, nullptr, N);
    // Layer 3
    k_agg<<<ga, 64, 0, stream>>>(h2, rs, csr, agg_a);
    k_gemm<1, 256><<<g3, 256, 0, stream>>>(agg_a, h2, bt3, sc3, sh3, nullptr, out, N);
}

// Round 4
// 272.511 us; speedup vs baseline: 1.0929x; 1.0123x over previous
//
#include <hip/hip_runtime.h>

#define NNODE 10000
#define NEDGE 160000

using frag8 = __attribute__((ext_vector_type(8))) short;
using f32x4 = __attribute__((ext_vector_type(4))) float;

__device__ __forceinline__ unsigned short f2bf(float f) {
    union { float f; unsigned u; } v; v.f = f;
    unsigned r = (v.u + 0x7fffu + ((v.u >> 16) & 1u)) >> 16;
    return (unsigned short)r;
}
__device__ __forceinline__ float bf2f(unsigned short s) {
    union { unsigned u; float f; } v; v.u = ((unsigned)s) << 16; return v.f;
}

// ---------------- scan ----------------
__global__ __launch_bounds__(1024) void k_scan(const int* __restrict__ deg,
                                               int* __restrict__ rs,
                                               int* __restrict__ cur, int n, int total) {
    const int tid = threadIdx.x;
    const int CH = 10;
    const int base = tid * CH;
    int vals[CH];
    int tsum = 0;
#pragma unroll
    for (int j = 0; j < CH; j++) {
        int v = (base + j < n) ? deg[base + j] : 0;
        vals[j] = v; tsum += v;
    }
    const int lane = tid & 63, wid = tid >> 6;
    int x = tsum;
#pragma unroll
    for (int d = 1; d < 64; d <<= 1) {
        int y = __shfl_up(x, d, 64);
        if (lane >= d) x += y;
    }
    __shared__ int wt[16];
    if (lane == 63) wt[wid] = x;
    __syncthreads();
    if (tid == 0) {
        int c = 0;
#pragma unroll
        for (int k = 0; k < 16; k++) { int t = wt[k]; wt[k] = c; c += t; }
    }
    __syncthreads();
    int run = wt[wid] + x - tsum;
#pragma unroll
    for (int j = 0; j < CH; j++) {
        if (base + j < n) { rs[base + j] = run; cur[base + j] = run; }
        run += vals[j];
    }
    if (tid == 0) rs[n] = total;
}

__global__ void k_fill(const int* __restrict__ src, const int* __restrict__ dst,
                       int E, int* __restrict__ cur, int* __restrict__ csr) {
    int e = blockIdx.x * 256 + threadIdx.x;
    if (e < E) {
        int p = atomicAdd(&cur[dst[e]], 1);
        csr[p] = src[e];
    }
}

// ---------------- fused prep: x-cast + weight transposes + scale/shift + edge count ----------------
// blocks [0,5000): cast x ; [5000,6280): transposes ; 6280: scale/shift ; [6281,6906): count
__global__ __launch_bounds__(256) void k_prep(
    const float* __restrict__ x, unsigned short* __restrict__ xb,
    const float* __restrict__ wl1, const float* __restrict__ wr1,
    const float* __restrict__ wl2, const float* __restrict__ wr2,
    const float* __restrict__ wl3, const float* __restrict__ wr3,
    unsigned short* __restrict__ bt1, unsigned short* __restrict__ bt2,
    unsigned short* __restrict__ bt3,
    const float* __restrict__ b1, const float* __restrict__ g1, const float* __restrict__ be1,
    const float* __restrict__ m1, const float* __restrict__ v1,
    const float* __restrict__ b2, const float* __restrict__ g2, const float* __restrict__ be2,
    const float* __restrict__ m2, const float* __restrict__ v2,
    const float* __restrict__ b3,
    float* __restrict__ sc1, float* __restrict__ sh1,
    float* __restrict__ sc2, float* __restrict__ sh2,
    float* __restrict__ sc3, float* __restrict__ sh3,
    const int* __restrict__ dstI, int* __restrict__ deg) {
    const int b = blockIdx.x, tid = threadIdx.x;
    if (b < 5000) {                       // x cast
        int i = b * 256 + tid;
        float4 f = ((const float4*)x)[i];
        ushort4 o;
        o.x = f2bf(f.x); o.y = f2bf(f.y); o.z = f2bf(f.z); o.w = f2bf(f.w);
        ((ushort4*)xb)[i] = o;
        return;
    }
    if (b >= 6281) {                      // edge degree count
        int e = (b - 6281) * 256 + tid;
        if (e < NEDGE) atomicAdd(&deg[dstI[e]], 1);
        return;
    }
    if (b == 6280) {                      // scale/shift
        for (int t = tid; t < 512; t += 256) {
            float s1 = g1[t] * rsqrtf(v1[t] + 1e-5f);
            sc1[t] = s1; sh1[t] = (b1[t] - m1[t]) * s1 + be1[t];
            float s2 = g2[t] * rsqrtf(v2[t] + 1e-5f);
            sc2[t] = s2; sh2[t] = (b2[t] - m2[t]) * s2 + be2[t];
        }
        if (tid < 256) { sc3[tid] = 1.0f; sh3[tid] = b3[tid]; }
        return;
    }
    // transposes: dst[n*1024 + koff + k] = src[k*C + n]
    __shared__ float t[32][33];
    int tj = b - 5000;
    const float* srcp; unsigned short* dstp; int C, koff, ntilesN;
    if (tj < 1024) {
        int job = tj >> 8; int tile = tj & 255; C = 512; ntilesN = 16;
        srcp = (job == 0) ? wl1 : (job == 1) ? wr1 : (job == 2) ? wl2 : wr2;
        dstp = (job < 2) ? bt1 : bt2; koff = (job & 1) * 512;
        tj = tile;
    } else {
        int jj = tj - 1024; int job = jj >> 7; int tile = jj & 127; C = 256; ntilesN = 8;
        srcp = (job == 0) ? wl3 : wr3; dstp = bt3; koff = job * 512;
        tj = tile;
    }
    int k0 = (tj / ntilesN) * 32, c0 = (tj % ntilesN) * 32;
    int tx = tid & 31, ty = tid >> 5;
#pragma unroll
    for (int q = 0; q < 4; q++)
        t[ty + 8 * q][tx] = srcp[(long)(k0 + ty + 8 * q) * C + c0 + tx];
    __syncthreads();
#pragma unroll
    for (int q = 0; q < 4; q++)
        dstp[(long)(c0 + ty + 8 * q) * 1024 + koff + k0 + tx] = f2bf(t[tx][ty + 8 * q]);
}

// ---------------- aggregation: 4 column passes, L2-resident ----------------
__global__ __launch_bounds__(64) void k_agg(const unsigned short* __restrict__ S,
                                            const int* __restrict__ rs, const int* __restrict__ csr,
                                            unsigned short* __restrict__ outb) {
    const int n = blockIdx.x;
    const int c = blockIdx.y * 128 + threadIdx.x * 2;
    const int s = rs[n], e = rs[n + 1];
    float a0 = 0.f, a1 = 0.f;
    int i = s;
    for (; i + 4 <= e; i += 4) {
        int r0 = csr[i], r1 = csr[i + 1], r2 = csr[i + 2], r3 = csr[i + 3];
        unsigned u0 = *(const unsigned*)(S + (long)r0 * 512 + c);
        unsigned u1 = *(const unsigned*)(S + (long)r1 * 512 + c);
        unsigned u2 = *(const unsigned*)(S + (long)r2 * 512 + c);
        unsigned u3 = *(const unsigned*)(S + (long)r3 * 512 + c);
        a0 += bf2f((unsigned short)(u0 & 0xffffu)); a1 += bf2f((unsigned short)(u0 >> 16));
        a0 += bf2f((unsigned short)(u1 & 0xffffu)); a1 += bf2f((unsigned short)(u1 >> 16));
        a0 += bf2f((unsigned short)(u2 & 0xffffu)); a1 += bf2f((unsigned short)(u2 >> 16));
        a0 += bf2f((unsigned short)(u3 & 0xffffu)); a1 += bf2f((unsigned short)(u3 >> 16));
    }
    for (; i < e; i++) {
        unsigned u = *(const unsigned*)(S + (long)csr[i] * 512 + c);
        a0 += bf2f((unsigned short)(u & 0xffffu)); a1 += bf2f((unsigned short)(u >> 16));
    }
    const int cnt = e - s;
    const float inv = 1.f / (float)(cnt > 1 ? cnt : 1);
    unsigned o = (unsigned)f2bf(a0 * inv) | ((unsigned)f2bf(a1 * inv) << 16);
    *(unsigned*)(outb + (long)n * 512 + c) = o;
}

// ---------------- GEMM with LDS double-buffering ----------------
// C[M x NOUT] = [Agg|Self][M x 1024] @ Bt[NOUT x 1024]^T, 128x64 tile, BK=64.
// MODE 0: relu(dot*sc+sh) -> bf16 stride 512 ; MODE 1: dot*sc+sh -> fp32 stride NOUT.
template <int MODE, int NOUT>
__global__ __launch_bounds__(256) void k_gemm(const unsigned short* __restrict__ Agg,
                                              const unsigned short* __restrict__ Self,
                                              const unsigned short* __restrict__ Bt,
                                              const float* __restrict__ sc, const float* __restrict__ sh,
                                              unsigned short* __restrict__ hout, float* __restrict__ fout,
                                              int M) {
    __shared__ __align__(16) short As[2][128 * 64];   // 32 KB
    __shared__ __align__(16) short Bs[2][64 * 64];    // 16 KB
    const int tid = threadIdx.x;
    const int m0 = blockIdx.x * 128, n0 = blockIdx.y * 64;
    const int w = tid >> 6, lane = tid & 63;
    const int wm = (w >> 1) * 64, wn = (w & 1) * 32;
    const int fr = lane & 15;
    const int fq = lane >> 4;
    const int sw = fr & 7;

    const int srow = w * 8 + (lane >> 3);
    const int scol = (((lane & 7) ^ (lane >> 3)) * 8);
    const int ldsOff = w * 8 * 64;

    f32x4 acc[4][2];
#pragma unroll
    for (int i = 0; i < 4; i++)
#pragma unroll
        for (int j = 0; j < 2; j++)
#pragma unroll
            for (int r = 0; r < 4; r++) acc[i][j][r] = 0.f;

    auto issue = [&](int t, int buf) {
        const short* abase = (const short*)((t < 8) ? Agg : Self);
        const int kk = (t & 7) * 64;
        const int k0 = t * 64;
#pragma unroll
        for (int cch = 0; cch < 4; cch++)
            __builtin_amdgcn_global_load_lds(
                (const __attribute__((address_space(1))) void*)(abase + (long)(m0 + cch * 32 + srow) * 512 + kk + scol),
                (__attribute__((address_space(3))) void*)(&As[buf][ldsOff + cch * 32 * 64]), 16, 0, 0);
#pragma unroll
        for (int cch = 0; cch < 2; cch++)
            __builtin_amdgcn_global_load_lds(
                (const __attribute__((address_space(1))) void*)((const short*)Bt + (long)(n0 + cch * 32 + srow) * 1024 + k0 + scol),
                (__attribute__((address_space(3))) void*)(&Bs[buf][ldsOff + cch * 32 * 64]), 16, 0, 0);
    };

    issue(0, 0);
#pragma unroll
    for (int t = 0; t < 16; t++) {
        const int cur = t & 1;
        __syncthreads();                  // drains DMA(t) [compiler emits vmcnt(0) here]
        if (t < 15) issue(t + 1, cur ^ 1);
#pragma unroll
        for (int ks = 0; ks < 2; ks++) {
            frag8 af[4], bf[2];
#pragma unroll
            for (int i = 0; i < 4; i++)
                af[i] = *(const frag8*)(&As[cur][(wm + i * 16 + fr) * 64 + (((ks * 4 + fq) ^ sw) * 8)]);
#pragma unroll
            for (int j = 0; j < 2; j++)
                bf[j] = *(const frag8*)(&Bs[cur][(wn + j * 16 + fr) * 64 + (((ks * 4 + fq) ^ sw) * 8)]);
#pragma unroll
            for (int i = 0; i < 4; i++)
#pragma unroll
                for (int j = 0; j < 2; j++)
                    acc[i][j] = __builtin_amdgcn_mfma_f32_16x16x32_bf16(af[i], bf[j], acc[i][j], 0, 0, 0);
        }
        __syncthreads();                  // compute(cur) done before DMA(t+2) overwrites it
    }

    float scj[2], shj[2];
#pragma unroll
    for (int j = 0; j < 2; j++) {
        int col = n0 + wn + j * 16 + fr;
        scj[j] = sc[col]; shj[j] = sh[col];
    }
#pragma unroll
    for (int i = 0; i < 4; i++) {
        int rowb = m0 + wm + i * 16 + fq * 4;
#pragma unroll
        for (int j = 0; j < 2; j++) {
            int col = n0 + wn + j * 16 + fr;
#pragma unroll
            for (int r = 0; r < 4; r++) {
                int row = rowb + r;
                if (row < M) {
                    float y = acc[i][j][r] * scj[j] + shj[j];
                    if constexpr (MODE == 0) {
                        y = fmaxf(y, 0.f);
                        hout[(long)row * 512 + col] = f2bf(y);
                    } else {
                        fout[(long)row * NOUT + col] = y;
                    }
                }
            }
        }
    }
}

extern "C" void kernel_launch(void* const* d_in, const int* in_sizes, int n_in,
                              void* d_out, int out_size, void* d_ws, size_t ws_size,
                              hipStream_t stream) {
    const float* x    = (const float*)d_in[0];
    const int*   ei   = (const int*)d_in[1];
    const float* w_l1 = (const float*)d_in[2];
    const float* b1   = (const float*)d_in[3];
    const float* w_r1 = (const float*)d_in[4];
    const float* g1   = (const float*)d_in[5];
    const float* be1  = (const float*)d_in[6];
    const float* m1   = (const float*)d_in[7];
    const float* v1   = (const float*)d_in[8];
    const float* w_l2 = (const float*)d_in[9];
    const float* b2   = (const float*)d_in[10];
    const float* w_r2 = (const float*)d_in[11];
    const float* g2   = (const float*)d_in[12];
    const float* be2  = (const float*)d_in[13];
    const float* m2   = (const float*)d_in[14];
    const float* v2   = (const float*)d_in[15];
    const float* w_l3 = (const float*)d_in[16];
    const float* b3   = (const float*)d_in[17];
    const float* w_r3 = (const float*)d_in[18];
    float* out = (float*)d_out;

    const int N = NNODE, E = NEDGE;
    const int* srcI = ei;
    const int* dstI = ei + E;

    char* w = (char*)d_ws;
    auto alloc = [&](size_t bytes) { void* p = (void*)w; w += (bytes + 255) & ~(size_t)255; return p; };
    int* deg = (int*)alloc((size_t)N * 4);
    int* rs  = (int*)alloc((size_t)(N + 1) * 4);
    int* cur = (int*)alloc((size_t)N * 4);
    int* csr = (int*)alloc((size_t)E * 4);
    unsigned short* xb   = (unsigned short*)alloc((size_t)N * 512 * 2);
    unsigned short* bt1  = (unsigned short*)alloc((size_t)512 * 1024 * 2);
    unsigned short* bt2  = (unsigned short*)alloc((size_t)512 * 1024 * 2);
    unsigned short* bt3  = (unsigned short*)alloc((size_t)256 * 1024 * 2);
    float* sc1 = (float*)alloc(512 * 4); float* sh1 = (float*)alloc(512 * 4);
    float* sc2 = (float*)alloc(512 * 4); float* sh2 = (float*)alloc(512 * 4);
    float* sc3 = (float*)alloc(256 * 4); float* sh3 = (float*)alloc(256 * 4);
    unsigned short* agg_a = (unsigned short*)alloc((size_t)N * 512 * 2);
    unsigned short* h1    = (unsigned short*)alloc((size_t)N * 512 * 2);
    unsigned short* h2    = (unsigned short*)alloc((size_t)N * 512 * 2);
    (void)alloc(256 * 1024);  // DMA over-read slack for last M-tile

    hipMemsetAsync(deg, 0, (size_t)N * 4, stream);
    k_prep<<<6906, 256, 0, stream>>>(x, xb, w_l1, w_r1, w_l2, w_r2, w_l3, w_r3,
                                     bt1, bt2, bt3,
                                     b1, g1, be1, m1, v1, b2, g2, be2, m2, v2, b3,
                                     sc1, sh1, sc2, sh2, sc3, sh3, dstI, deg);
    k_scan<<<1, 1024, 0, stream>>>(deg, rs, cur, N, E);
    k_fill<<<(E + 255) / 256, 256, 0, stream>>>(srcI, dstI, E, cur, csr);

    dim3 g12((N + 127) / 128, 8);
    dim3 g3((N + 127) / 128, 4);
    dim3 ga(N, 4);

    // Layer 1
    k_agg<<<ga, 64, 0, stream>>>(xb, rs, csr, agg_a);
    k_gemm<0, 512><<<g12, 256, 0, stream>>>(agg_a, xb, bt1, sc1, sh1, h1, nullptr, N);
    // Layer 2
    k_agg<<<ga, 64, 0, stream>>>(h1, rs, csr, agg_a);
    k_gemm<0, 512><<<g12, 256, 0, stream>>>(agg_a, h1, bt2, sc2, sh2, h2, nullptr, N);
    // Layer 3
    k_agg<<<ga, 64, 0, stream>>>(h2, rs, csr, agg_a);
    k_gemm<1, 256><<<g3, 256, 0, stream>>>(agg_a, h2, bt3, sc3, sh3, nullptr, out, N);
}

// Round 5
// 251.756 us; speedup vs baseline: 1.1830x; 1.0824x over previous
//
#include <hip/hip_runtime.h>

#define NNODE 10000
#define NEDGE 160000

using frag8 = __attribute__((ext_vector_type(8))) short;
using f32x4 = __attribute__((ext_vector_type(4))) float;

__device__ __forceinline__ unsigned short f2bf(float f) {
    union { float f; unsigned u; } v; v.f = f;
    unsigned r = (v.u + 0x7fffu + ((v.u >> 16) & 1u)) >> 16;
    return (unsigned short)r;
}
__device__ __forceinline__ float bf2f(unsigned short s) {
    union { unsigned u; float f; } v; v.u = ((unsigned)s) << 16; return v.f;
}

// ---------------- scan ----------------
__global__ __launch_bounds__(1024) void k_scan(const int* __restrict__ deg,
                                               int* __restrict__ rs,
                                               int* __restrict__ cur, int n, int total) {
    const int tid = threadIdx.x;
    const int CH = 10;
    const int base = tid * CH;
    int vals[CH];
    int tsum = 0;
#pragma unroll
    for (int j = 0; j < CH; j++) {
        int v = (base + j < n) ? deg[base + j] : 0;
        vals[j] = v; tsum += v;
    }
    const int lane = tid & 63, wid = tid >> 6;
    int x = tsum;
#pragma unroll
    for (int d = 1; d < 64; d <<= 1) {
        int y = __shfl_up(x, d, 64);
        if (lane >= d) x += y;
    }
    __shared__ int wt[16];
    if (lane == 63) wt[wid] = x;
    __syncthreads();
    if (tid == 0) {
        int c = 0;
#pragma unroll
        for (int k = 0; k < 16; k++) { int t = wt[k]; wt[k] = c; c += t; }
    }
    __syncthreads();
    int run = wt[wid] + x - tsum;
#pragma unroll
    for (int j = 0; j < CH; j++) {
        if (base + j < n) { rs[base + j] = run; cur[base + j] = run; }
        run += vals[j];
    }
    if (tid == 0) rs[n] = total;
}

__global__ void k_fill(const int* __restrict__ src, const int* __restrict__ dst,
                       int E, int* __restrict__ cur, int* __restrict__ csr) {
    int e = blockIdx.x * 256 + threadIdx.x;
    if (e < E) {
        int p = atomicAdd(&cur[dst[e]], 1);
        csr[p] = src[e];
    }
}

// ---------------- fused prep: x-cast + weight transposes + scale/shift + edge count ----------------
__global__ __launch_bounds__(256) void k_prep(
    const float* __restrict__ x, unsigned short* __restrict__ xb,
    const float* __restrict__ wl1, const float* __restrict__ wr1,
    const float* __restrict__ wl2, const float* __restrict__ wr2,
    const float* __restrict__ wl3, const float* __restrict__ wr3,
    unsigned short* __restrict__ bt1, unsigned short* __restrict__ bt2,
    unsigned short* __restrict__ bt3,
    const float* __restrict__ b1, const float* __restrict__ g1, const float* __restrict__ be1,
    const float* __restrict__ m1, const float* __restrict__ v1,
    const float* __restrict__ b2, const float* __restrict__ g2, const float* __restrict__ be2,
    const float* __restrict__ m2, const float* __restrict__ v2,
    const float* __restrict__ b3,
    float* __restrict__ sc1, float* __restrict__ sh1,
    float* __restrict__ sc2, float* __restrict__ sh2,
    float* __restrict__ sc3, float* __restrict__ sh3,
    const int* __restrict__ dstI, int* __restrict__ deg) {
    const int b = blockIdx.x, tid = threadIdx.x;
    if (b < 5000) {                       // x cast
        int i = b * 256 + tid;
        float4 f = ((const float4*)x)[i];
        ushort4 o;
        o.x = f2bf(f.x); o.y = f2bf(f.y); o.z = f2bf(f.z); o.w = f2bf(f.w);
        ((ushort4*)xb)[i] = o;
        return;
    }
    if (b >= 6281) {                      // edge degree count
        int e = (b - 6281) * 256 + tid;
        if (e < NEDGE) atomicAdd(&deg[dstI[e]], 1);
        return;
    }
    if (b == 6280) {                      // scale/shift
        for (int t = tid; t < 512; t += 256) {
            float s1 = g1[t] * rsqrtf(v1[t] + 1e-5f);
            sc1[t] = s1; sh1[t] = (b1[t] - m1[t]) * s1 + be1[t];
            float s2 = g2[t] * rsqrtf(v2[t] + 1e-5f);
            sc2[t] = s2; sh2[t] = (b2[t] - m2[t]) * s2 + be2[t];
        }
        if (tid < 256) { sc3[tid] = 1.0f; sh3[tid] = b3[tid]; }
        return;
    }
    __shared__ float t[32][33];
    int tj = b - 5000;
    const float* srcp; unsigned short* dstp; int C, koff, ntilesN;
    if (tj < 1024) {
        int job = tj >> 8; int tile = tj & 255; C = 512; ntilesN = 16;
        srcp = (job == 0) ? wl1 : (job == 1) ? wr1 : (job == 2) ? wl2 : wr2;
        dstp = (job < 2) ? bt1 : bt2; koff = (job & 1) * 512;
        tj = tile;
    } else {
        int jj = tj - 1024; int job = jj >> 7; int tile = jj & 127; C = 256; ntilesN = 8;
        srcp = (job == 0) ? wl3 : wr3; dstp = bt3; koff = job * 512;
        tj = tile;
    }
    int k0 = (tj / ntilesN) * 32, c0 = (tj % ntilesN) * 32;
    int tx = tid & 31, ty = tid >> 5;
#pragma unroll
    for (int q = 0; q < 4; q++)
        t[ty + 8 * q][tx] = srcp[(long)(k0 + ty + 8 * q) * C + c0 + tx];
    __syncthreads();
#pragma unroll
    for (int q = 0; q < 4; q++)
        dstp[(long)(c0 + ty + 8 * q) * 1024 + koff + k0 + tx] = f2bf(t[tx][ty + 8 * q]);
}

// ---------------- aggregation: 4 column passes, L2-resident ----------------
__global__ __launch_bounds__(64) void k_agg(const unsigned short* __restrict__ S,
                                            const int* __restrict__ rs, const int* __restrict__ csr,
                                            unsigned short* __restrict__ outb) {
    const int n = blockIdx.x;
    const int c = blockIdx.y * 128 + threadIdx.x * 2;
    const int s = rs[n], e = rs[n + 1];
    float a0 = 0.f, a1 = 0.f;
    int i = s;
    for (; i + 4 <= e; i += 4) {
        int r0 = csr[i], r1 = csr[i + 1], r2 = csr[i + 2], r3 = csr[i + 3];
        unsigned u0 = *(const unsigned*)(S + (long)r0 * 512 + c);
        unsigned u1 = *(const unsigned*)(S + (long)r1 * 512 + c);
        unsigned u2 = *(const unsigned*)(S + (long)r2 * 512 + c);
        unsigned u3 = *(const unsigned*)(S + (long)r3 * 512 + c);
        a0 += bf2f((unsigned short)(u0 & 0xffffu)); a1 += bf2f((unsigned short)(u0 >> 16));
        a0 += bf2f((unsigned short)(u1 & 0xffffu)); a1 += bf2f((unsigned short)(u1 >> 16));
        a0 += bf2f((unsigned short)(u2 & 0xffffu)); a1 += bf2f((unsigned short)(u2 >> 16));
        a0 += bf2f((unsigned short)(u3 & 0xffffu)); a1 += bf2f((unsigned short)(u3 >> 16));
    }
    for (; i < e; i++) {
        unsigned u = *(const unsigned*)(S + (long)csr[i] * 512 + c);
        a0 += bf2f((unsigned short)(u & 0xffffu)); a1 += bf2f((unsigned short)(u >> 16));
    }
    const int cnt = e - s;
    const float inv = 1.f / (float)(cnt > 1 ? cnt : 1);
    unsigned o = (unsigned)f2bf(a0 * inv) | ((unsigned)f2bf(a1 * inv) << 16);
    *(unsigned*)(outb + (long)n * 512 + c) = o;
}

// ---------------- GEMM, XCD-ownership swizzle + LDS double-buffering ----------------
// C[M x NOUT] = [Agg|Self][M x 1024] @ Bt[NOUT x 1024]^T, 128x64 tile, BK=64.
// Flat grid; XCD X (= blockIdx%8) owns m-strips === X (mod 8), iterating n-tiles fastest,
// so each XCD's L2 holds its A-strips (~2.5MB) + full B (1-2MB): A hits L3 only once.
// MODE 0: relu(dot*sc+sh) -> bf16 stride 512 ; MODE 1: dot*sc+sh -> fp32 stride NOUT.
template <int MODE, int NOUT>
__global__ __launch_bounds__(256) void k_gemm(const unsigned short* __restrict__ Agg,
                                              const unsigned short* __restrict__ Self,
                                              const unsigned short* __restrict__ Bt,
                                              const float* __restrict__ sc, const float* __restrict__ sh,
                                              unsigned short* __restrict__ hout, float* __restrict__ fout,
                                              int M) {
    constexpr int NT = NOUT / 64;         // n-tiles: 8 or 4
    constexpr int QSH = (NT == 8) ? 6 : 5; // 3 + log2(NT)
    const int b = blockIdx.x;
    const int X = b & 7;
    const int q = (b >> 3) & (NT - 1);
    const int g = b >> QSH;
    const int mstrip = g * 8 + X;
    const int m0 = mstrip * 128;
    if (m0 >= M) return;
    const int n0 = q * 64;

    __shared__ __align__(16) short As[2][128 * 64];
    __shared__ __align__(16) short Bs[2][64 * 64];
    const int tid = threadIdx.x;
    const int w = tid >> 6, lane = tid & 63;
    const int wm = (w >> 1) * 64, wn = (w & 1) * 32;
    const int fr = lane & 15;
    const int fq = lane >> 4;
    const int sw = fr & 7;

    const int srow = w * 8 + (lane >> 3);
    const int scol = (((lane & 7) ^ (lane >> 3)) * 8);
    const int ldsOff = w * 8 * 64;

    f32x4 acc[4][2];
#pragma unroll
    for (int i = 0; i < 4; i++)
#pragma unroll
        for (int j = 0; j < 2; j++)
#pragma unroll
            for (int r = 0; r < 4; r++) acc[i][j][r] = 0.f;

    auto issue = [&](int t, int buf) {
        const short* abase = (const short*)((t < 8) ? Agg : Self);
        const int kk = (t & 7) * 64;
        const int k0 = t * 64;
#pragma unroll
        for (int cch = 0; cch < 4; cch++)
            __builtin_amdgcn_global_load_lds(
                (const __attribute__((address_space(1))) void*)(abase + (long)(m0 + cch * 32 + srow) * 512 + kk + scol),
                (__attribute__((address_space(3))) void*)(&As[buf][ldsOff + cch * 32 * 64]), 16, 0, 0);
#pragma unroll
        for (int cch = 0; cch < 2; cch++)
            __builtin_amdgcn_global_load_lds(
                (const __attribute__((address_space(1))) void*)((const short*)Bt + (long)(n0 + cch * 32 + srow) * 1024 + k0 + scol),
                (__attribute__((address_space(3))) void*)(&Bs[buf][ldsOff + cch * 32 * 64]), 16, 0, 0);
    };

    issue(0, 0);
#pragma unroll
    for (int t = 0; t < 16; t++) {
        const int cur = t & 1;
        __syncthreads();
        if (t < 15) issue(t + 1, cur ^ 1);
#pragma unroll
        for (int ks = 0; ks < 2; ks++) {
            frag8 af[4], bf[2];
#pragma unroll
            for (int i = 0; i < 4; i++)
                af[i] = *(const frag8*)(&As[cur][(wm + i * 16 + fr) * 64 + (((ks * 4 + fq) ^ sw) * 8)]);
#pragma unroll
            for (int j = 0; j < 2; j++)
                bf[j] = *(const frag8*)(&Bs[cur][(wn + j * 16 + fr) * 64 + (((ks * 4 + fq) ^ sw) * 8)]);
#pragma unroll
            for (int i = 0; i < 4; i++)
#pragma unroll
                for (int j = 0; j < 2; j++)
                    acc[i][j] = __builtin_amdgcn_mfma_f32_16x16x32_bf16(af[i], bf[j], acc[i][j], 0, 0, 0);
        }
        __syncthreads();
    }

    float scj[2], shj[2];
#pragma unroll
    for (int j = 0; j < 2; j++) {
        int col = n0 + wn + j * 16 + fr;
        scj[j] = sc[col]; shj[j] = sh[col];
    }
#pragma unroll
    for (int i = 0; i < 4; i++) {
        int rowb = m0 + wm + i * 16 + fq * 4;
#pragma unroll
        for (int j = 0; j < 2; j++) {
            int col = n0 + wn + j * 16 + fr;
#pragma unroll
            for (int r = 0; r < 4; r++) {
                int row = rowb + r;
                if (row < M) {
                    float y = acc[i][j][r] * scj[j] + shj[j];
                    if constexpr (MODE == 0) {
                        y = fmaxf(y, 0.f);
                        hout[(long)row * 512 + col] = f2bf(y);
                    } else {
                        fout[(long)row * NOUT + col] = y;
                    }
                }
            }
        }
    }
}

extern "C" void kernel_launch(void* const* d_in, const int* in_sizes, int n_in,
                              void* d_out, int out_size, void* d_ws, size_t ws_size,
                              hipStream_t stream) {
    const float* x    = (const float*)d_in[0];
    const int*   ei   = (const int*)d_in[1];
    const float* w_l1 = (const float*)d_in[2];
    const float* b1   = (const float*)d_in[3];
    const float* w_r1 = (const float*)d_in[4];
    const float* g1   = (const float*)d_in[5];
    const float* be1  = (const float*)d_in[6];
    const float* m1   = (const float*)d_in[7];
    const float* v1   = (const float*)d_in[8];
    const float* w_l2 = (const float*)d_in[9];
    const float* b2   = (const float*)d_in[10];
    const float* w_r2 = (const float*)d_in[11];
    const float* g2   = (const float*)d_in[12];
    const float* be2  = (const float*)d_in[13];
    const float* m2   = (const float*)d_in[14];
    const float* v2   = (const float*)d_in[15];
    const float* w_l3 = (const float*)d_in[16];
    const float* b3   = (const float*)d_in[17];
    const float* w_r3 = (const float*)d_in[18];
    float* out = (float*)d_out;

    const int N = NNODE, E = NEDGE;
    const int* srcI = ei;
    const int* dstI = ei + E;

    char* w = (char*)d_ws;
    auto alloc = [&](size_t bytes) { void* p = (void*)w; w += (bytes + 255) & ~(size_t)255; return p; };
    int* deg = (int*)alloc((size_t)N * 4);
    int* rs  = (int*)alloc((size_t)(N + 1) * 4);
    int* cur = (int*)alloc((size_t)N * 4);
    int* csr = (int*)alloc((size_t)E * 4);
    unsigned short* xb   = (unsigned short*)alloc((size_t)N * 512 * 2);
    unsigned short* bt1  = (unsigned short*)alloc((size_t)512 * 1024 * 2);
    unsigned short* bt2  = (unsigned short*)alloc((size_t)512 * 1024 * 2);
    unsigned short* bt3  = (unsigned short*)alloc((size_t)256 * 1024 * 2);
    float* sc1 = (float*)alloc(512 * 4); float* sh1 = (float*)alloc(512 * 4);
    float* sc2 = (float*)alloc(512 * 4); float* sh2 = (float*)alloc(512 * 4);
    float* sc3 = (float*)alloc(256 * 4); float* sh3 = (float*)alloc(256 * 4);
    unsigned short* agg_a = (unsigned short*)alloc((size_t)N * 512 * 2);
    unsigned short* h1    = (unsigned short*)alloc((size_t)N * 512 * 2);
    unsigned short* h2    = (unsigned short*)alloc((size_t)N * 512 * 2);
    (void)alloc(256 * 1024);  // DMA over-read slack for last M-tile

    hipMemsetAsync(deg, 0, (size_t)N * 4, stream);
    k_prep<<<6906, 256, 0, stream>>>(x, xb, w_l1, w_r1, w_l2, w_r2, w_l3, w_r3,
                                     bt1, bt2, bt3,
                                     b1, g1, be1, m1, v1, b2, g2, be2, m2, v2, b3,
                                     sc1, sh1, sc2, sh2, sc3, sh3, dstI, deg);
    k_scan<<<1, 1024, 0, stream>>>(deg, rs, cur, N, E);
    k_fill<<<(E + 255) / 256, 256, 0, stream>>>(srcI, dstI, E, cur, csr);

    // grids: layer1/2: ceil(79/8)=10 strip-groups * 8 XCD * 8 n-tiles = 640
    //        layer3:   10 * 8 * 4 = 320
    dim3 ga(N, 4);

    // Layer 1
    k_agg<<<ga, 64, 0, stream>>>(xb, rs, csr, agg_a);
    k_gemm<0, 512><<<640, 256, 0, stream>>>(agg_a, xb, bt1, sc1, sh1, h1, nullptr, N);
    // Layer 2
    k_agg<<<ga, 64, 0, stream>>>(h1, rs, csr, agg_a);
    k_gemm<0, 512><<<640, 256, 0, stream>>>(agg_a, h1, bt2, sc2, sh2, h2, nullptr, N);
    // Layer 3
    k_agg<<<ga, 64, 0, stream>>>(h2, rs, csr, agg_a);
    k_gemm<1, 256><<<320, 256, 0, stream>>>(agg_a, h2, bt3, sc3, sh3, nullptr, out, N);
}